// Round 19
// baseline (249.895 us; speedup 1.0000x reference)
//
#include <hip/hip_runtime.h>
#include <math.h>

#define NROWS 65536
#define KCODES 1024
#define DDIM 256
#define ND_TOT (NROWS * DDIM)

// ---------- ws layout (bytes) ----------
#define WS_IDX      0         // int idx[N]          256KB
#define WS_COUNTS   262144    // int counts[K]       4KB
#define WS_SW       266240    // float sw[K]         4KB
#define WS_PARTQ    532480    // float partQ[1024]   4KB
#define WS_PARTP    536576    // float partP[1024]   4KB
#define WS_FLAGCNT  540672    // int                 (256B slot)
#define WS_FLAGLIST 540928    // int flagList[N]     256KB
#define WS_WH       803072    // ushort wh[K*256]    512KB
#define WS_WL       1327360   // ushort wl[K*256]    512KB

typedef float f32x4 __attribute__((ext_vector_type(4)));
typedef short bf16x8 __attribute__((ext_vector_type(8)));

__device__ inline unsigned short f2bf(float f) {
  unsigned u = __float_as_uint(f);
  u += 0x7FFFu + ((u >> 16) & 1u);   // RNE to bf16
  return (unsigned short)(u >> 16);
}
__device__ inline float bf2f(unsigned short h) {
  return __uint_as_float(((unsigned)h) << 16);
}

__device__ inline void gload16(const void* g, void* l) {
  __builtin_amdgcn_global_load_lds((const __attribute__((address_space(1))) void*)g,
                                   (__attribute__((address_space(3))) void*)l, 16, 0, 0);
}

// ========== fused prep ==========
// blocks [0,2048):      x bf16-split, batched loads; block 0 zeroes counts+flagCnt
// blocks [2048,2304):   w prep: coalesced split + exact numpy-pairwise sw (lane chains)
// blocks [2304,4384):   self-sufficient tiled compactness (16x16-pair tiles; only reads w;
//                       tile sums -> atomicAdd into partialP[tile&1023], memset'd beforehand)
__global__ __launch_bounds__(256) void vq_prep(const float* __restrict__ x,
                                               const float* __restrict__ w,
                                               unsigned short* __restrict__ xh,
                                               unsigned short* __restrict__ xl,
                                               float* __restrict__ sw,
                                               unsigned short* __restrict__ wh,
                                               unsigned short* __restrict__ wl,
                                               int* __restrict__ counts,
                                               int* __restrict__ flagCnt,
                                               float* __restrict__ partialP) {
#pragma clang fp contract(off)
  const int b = blockIdx.x;
  const int t = threadIdx.x;
  if (b >= 2304) {
    // ---- compactness: 16x16-pair tiles over upper triangle (incl. diagonal tiles) ----
    __shared__ __align__(16) float wI[16][260];
    __shared__ __align__(16) float wJ[16][260];
    int tb = b - 2304, ti = 0;
    while (tb >= 64 - ti) { tb -= 64 - ti; ++ti; }
    const int tj = ti + tb;
    const int lane = t & 63, wvid = t >> 6;
#pragma unroll
    for (int k = 0; k < 4; ++k) {
      const int q = k * 256 + t;
      const int r = q >> 6, c4 = q & 63;
      float4 vI = *(const float4*)&w[(size_t)(ti * 16 + r) * DDIM + c4 * 4];
      float4 vJ = *(const float4*)&w[(size_t)(tj * 16 + r) * DDIM + c4 * 4];
      *(float4*)&wI[r][c4 * 4] = vI;
      *(float4*)&wJ[r][c4 * 4] = vJ;
    }
    __syncthreads();
    const int ii = t & 15, jj = t >> 4;
    const int gi = ti * 16 + ii, gj = tj * 16 + jj;
    double s = 0.0;
    if (gi < gj) {
      float dot = 0.f, sqa = 0.f, sqb = 0.f;
      for (int d4 = 0; d4 < DDIM / 4; ++d4) {
        const float4 A = *(const float4*)&wI[ii][d4 * 4];
        const float4 B = *(const float4*)&wJ[jj][d4 * 4];
        dot += A.x * B.x + A.y * B.y + A.z * B.z + A.w * B.w;
        sqa += A.x * A.x + A.y * A.y + A.z * A.z + A.w * A.w;
        sqb += B.x * B.x + B.y * B.y + B.z * B.z + B.w * B.w;
      }
      const float pd2 = (sqa + sqb) - 2.0f * dot;
      s = (double)sqrtf(fmaxf(pd2, 1e-12f));
    }
    for (int off = 32; off > 0; off >>= 1) s += __shfl_down(s, off);
    __shared__ double redc[4];
    if (lane == 0) redc[wvid] = s;
    __syncthreads();
    if (t == 0)
      atomicAdd(&partialP[(b - 2304) & 1023], (float)(redc[0] + redc[1] + redc[2] + redc[3]));
    return;
  }
  if (b >= 2048) {
    const int lane = t & 63, wv = t >> 6;
    const int row = (b - 2048) * 4 + wv;           // 256 blocks x 4 rows = 1024
    const float* src = w + (size_t)row * DDIM;
    float4 v4 = *(const float4*)&src[lane * 4];    // full row per wave, coalesced
    float fv[4] = {v4.x, v4.y, v4.z, v4.w};
    union { unsigned short us[4]; uint2 v; } ph, pl;
#pragma unroll
    for (int e = 0; e < 4; ++e) {
      unsigned short h = f2bf(fv[e]);
      ph.us[e] = h;
      pl.us[e] = f2bf(fv[e] - bf2f(h));
    }
    *(uint2*)&wh[(size_t)row * DDIM + lane * 4] = ph.v;
    *(uint2*)&wl[(size_t)row * DDIM + lane * 4] = pl.v;
    // exact sw: numpy pairwise_sum(256) = two 128-halves x 8 accumulators.
    float acc = 0.f;
    if (lane < 16) {
      const float* p = src + ((lane >> 3) & 1) * 128 + (lane & 7);
      float v = p[0];
      acc = v * v;
      for (int k = 1; k < 16; ++k) { float vv = p[k * 8]; float e = vv * vv; acc = acc + e; }
    }
    // tree combine in reference association order ((a0+a1)+(a2+a3))+((a4+a5)+(a6+a7))
    acc = acc + __shfl_xor(acc, 1);
    acc = acc + __shfl_xor(acc, 2);
    acc = acc + __shfl_xor(acc, 4);
    const float hb = __shfl(acc, 8);               // half-1 total sits at lane 8
    if (lane == 0) sw[row] = acc + hb;
    return;
  }
  if (b == 0) {
#pragma unroll
    for (int j = 0; j < 4; ++j) counts[j * 256 + t] = 0;
    if (t == 0) flagCnt[0] = 0;
  }
  // ---- x split: batch all 8 loads before converting (4x outstanding loads/wave) ----
  const size_t tid = (size_t)b * 256 + t;
  float4 a[4], c[4];
#pragma unroll
  for (int g = 0; g < 4; ++g) {
    const size_t e = ((size_t)g * 524288 + tid) * 8;
    a[g] = *(const float4*)&x[e];
    c[g] = *(const float4*)&x[e + 4];
  }
#pragma unroll
  for (int g = 0; g < 4; ++g) {
    const size_t e = ((size_t)g * 524288 + tid) * 8;
    float fv[8] = {a[g].x, a[g].y, a[g].z, a[g].w, c[g].x, c[g].y, c[g].z, c[g].w};
    union { unsigned short us[8]; uint4 v; } ph, pl;
#pragma unroll
    for (int k = 0; k < 8; ++k) {
      unsigned short h = f2bf(fv[k]);
      ph.us[k] = h;
      pl.us[k] = f2bf(fv[k] - bf2f(h));   // exact in fp32
    }
    *(uint4*)&xh[e] = ph.v;
    *(uint4*)&xl[e] = pl.v;
  }
}

// ========== MFMA split-bf16 distance + top2 argmin (R14/R16 structure, proven 110us) ==========
// x-fragments in registers for full K; single-buffer w staging, 2 barriers/dt.
// NOTE (R17 lesson): double-buffered pipelining of this loop spills (WRITE_SIZE 90MB)
// and regresses to 152us — do not re-attempt at source level.
#define TRM 128
#define BKM 64
// Flag threshold: hard bound for a reference-order flip is
//   approx-e error (<=~6e-6) + reference rounding reorder width (~6.1e-5).
// Total ~7.3e-5; T=1.5e-4 keeps 2x margin.
#define REPAIR_T 1.5e-4f

__global__ __launch_bounds__(256, 2) void vq_argmin_mfma(
    const unsigned short* __restrict__ xh, const unsigned short* __restrict__ xl,
    const unsigned short* __restrict__ wh, const unsigned short* __restrict__ wl,
    const float* __restrict__ sw,
    int* __restrict__ idxOut, float* __restrict__ idxOutF,
    int* __restrict__ flagCnt, int* __restrict__ flagList) {
  __shared__ __align__(16) unsigned short lds_wh[TRM * BKM];  // 16KB each, XOR-swizzled
  __shared__ __align__(16) unsigned short lds_wl[TRM * BKM];
  __shared__ __align__(16) float sws[KCODES];
  __shared__ float mrgB1[TRM];
  __shared__ float mrgB2[TRM];
  __shared__ int   mrgI[TRM];

  const int t = threadIdx.x;
  const int lane = t & 63, wv = t >> 6;   // 4 waves; wave owns rows [wv*32, wv*32+32)
  const int row0 = blockIdx.x * TRM;

  { f32x4 v = ((const f32x4*)sw)[t]; ((f32x4*)sws)[t] = v; }  // 1024 floats

  const int laneRow = lane >> 3;                                  // 0..7
  const int srcswz = ((lane & 7) * 16) ^ ((laneRow & 7) << 4);    // pre-swizzled source chunk
  const char* whB = (const char*)wh;
  const char* wlB = (const char*)wl;

  // ---- one-time x fragment preload: register image == what the LDS path produced ----
  bf16x8 ah[2][8], al[2][8];
  {
    const int rbase = row0 + wv * 32 + (lane & 15);
    const int kof = ((lane >> 4) & 3) * 8;
#pragma unroll
    for (int i = 0; i < 2; ++i)
#pragma unroll
      for (int ks = 0; ks < 8; ++ks) {
        const size_t e = (size_t)(rbase + i * 16) * DDIM + (size_t)(ks * 32 + kof);
        ah[i][ks] = *(const bf16x8*)&xh[e];
        al[i][ks] = *(const bf16x8*)&xl[e];
      }
  }

  float b1[8], b2[8];
  int bi[8];
#pragma unroll
  for (int s = 0; s < 8; ++s) { b1[s] = 3.4e38f; b2[s] = 3.4e38f; bi[s] = 0; }

  for (int ct = 0; ct < KCODES / TRM; ++ct) {
    f32x4 acc[2][8];
#pragma unroll
    for (int i = 0; i < 2; ++i)
#pragma unroll
      for (int j = 0; j < 8; ++j) acc[i][j] = (f32x4){0.f, 0.f, 0.f, 0.f};

    for (int dt = 0; dt < 4; ++dt) {
      __syncthreads();   // previous tile fully consumed
#pragma unroll
      for (int i = 0; i < 4; ++i) {
        const int rb = wv * 32 + i * 8;
        const size_t gow = (size_t)(ct * 128 + rb + laneRow) * 512 + (size_t)(dt * 128 + srcswz);
        gload16(whB + gow, (char*)lds_wh + rb * 128);
        gload16(wlB + gow, (char*)lds_wl + rb * 128);
      }
      __syncthreads();   // drains vmcnt + barrier

#pragma unroll
      for (int kh = 0; kh < 2; ++kh) {
        const int kb = kh * 64 + ((lane >> 4) & 3) * 16;
        const int ks = dt * 2 + kh;
#pragma unroll
        for (int j = 0; j < 8; ++j) {
          const int c = j * 16 + (lane & 15);
          const int off = c * 128 + (kb ^ ((c & 7) << 4));
          bf16x8 bh = *(const bf16x8*)((const char*)lds_wh + off);
          bf16x8 bl = *(const bf16x8*)((const char*)lds_wl + off);
#pragma unroll
          for (int i = 0; i < 2; ++i) {
            acc[i][j] = __builtin_amdgcn_mfma_f32_16x16x32_bf16(ah[i][ks], bh, acc[i][j], 0, 0, 0);
            acc[i][j] = __builtin_amdgcn_mfma_f32_16x16x32_bf16(ah[i][ks], bl, acc[i][j], 0, 0, 0);
            acc[i][j] = __builtin_amdgcn_mfma_f32_16x16x32_bf16(al[i][ks], bh, acc[i][j], 0, 0, 0);
          }
        }
      }
    }

    // top-2 update in e-space: e = sw - 2*dot  (sx drops out of per-row argmin)
#pragma unroll
    for (int j = 0; j < 8; ++j) {
      const int colbase = ct * 128 + j * 16 + (lane & 15);
      const float swv = sws[colbase];
#pragma unroll
      for (int i = 0; i < 2; ++i)
#pragma unroll
        for (int q = 0; q < 4; ++q) {
          const int s = i * 4 + q;
          const float e = fmaf(-2.f, acc[i][j][q], swv);
          const bool c1 = e < b1[s];
          b2[s] = c1 ? b1[s] : fminf(b2[s], e);
          bi[s] = c1 ? colbase : bi[s];
          b1[s] = fminf(b1[s], e);
        }
    }
  }

  // merge across the 16 lanes sharing rows (lane&15 varies = different cols)
#pragma unroll
  for (int off = 1; off < 16; off <<= 1) {
#pragma unroll
    for (int s = 0; s < 8; ++s) {
      const float ob1 = __shfl_xor(b1[s], off);
      const float ob2 = __shfl_xor(b2[s], off);
      const int oi = __shfl_xor(bi[s], off);
      const float hi = fmaxf(b1[s], ob1);
      const bool take = ob1 < b1[s];
      b1[s] = fminf(b1[s], ob1);
      b2[s] = fminf(hi, fminf(b2[s], ob2));
      bi[s] = take ? oi : bi[s];
    }
  }
  if ((lane & 15) == 0) {
#pragma unroll
    for (int i = 0; i < 2; ++i)
#pragma unroll
      for (int q = 0; q < 4; ++q) {
        const int s = i * 4 + q;
        const int r = wv * 32 + i * 16 + ((lane >> 4) & 3) * 4 + q;
        mrgB1[r] = b1[s]; mrgB2[r] = b2[s]; mrgI[r] = bi[s];
      }
  }
  __syncthreads();
  if (t < TRM) {
    const float b1f = mrgB1[t];
    const float b2f = mrgB2[t];
    const int idxf = mrgI[t];
    const int grow = row0 + t;
    idxOut[grow] = idxf;
    idxOutF[grow] = (float)idxf;
    const bool flag = (b2f - b1f) < REPAIR_T;
    unsigned long long m = __ballot(flag);
    int base2 = 0;
    if ((t & 63) == 0) base2 = atomicAdd(flagCnt, __popcll(m));
    base2 = __shfl(base2, 0);
    if (flag) flagList[base2 + __popcll(m & ((1ull << (t & 63)) - 1ull))] = grow;
  }
}

// ========== exact repair of flagged rows (proven inner structure, standalone) ==========
#define RPB 8
__global__ __launch_bounds__(256) void vq_repair(
    const float* __restrict__ x, const float* __restrict__ w,
    const float* __restrict__ sw,
    const int* __restrict__ flagCnt, const int* __restrict__ flagList,
    int* __restrict__ idxOut, float* __restrict__ idxOutF) {
  const int t = threadIdx.x;
  const int lane = t & 63, wvid = t >> 6;
  __shared__ __align__(16) float xrow[RPB][DDIM];
  __shared__ float sxsh[RPB];
  __shared__ float redD[RPB][4];
  __shared__ int   redI[RPB][4];
  const int cnt = flagCnt[0];
  for (int base = blockIdx.x * RPB; base < cnt; base += 1024 * RPB) {
    const int nr = min(RPB, cnt - base);
    __syncthreads();   // protect xrow/redD from previous pass readers
    for (int r = 0; r < nr; ++r)
      xrow[r][t] = x[(size_t)flagList[base + r] * DDIM + t];
    __syncthreads();
    // exact sx for this row: numpy pairwise order, no FMA
    if (t < nr) {
#pragma clang fp contract(off)
      float halves[2];
#pragma unroll
      for (int h = 0; h < 2; ++h) {
        const float* p = &xrow[t][h * 128];
        float acc[8];
#pragma unroll
        for (int j = 0; j < 8; ++j) { float v = p[j]; acc[j] = v * v; }
        for (int i = 8; i < 128; i += 8) {
#pragma unroll
          for (int j = 0; j < 8; ++j) { float v = p[i + j]; float e = v * v; acc[j] = acc[j] + e; }
        }
        halves[h] = ((acc[0] + acc[1]) + (acc[2] + acc[3])) + ((acc[4] + acc[5]) + (acc[6] + acc[7]));
      }
      sxsh[t] = halves[0] + halves[1];
    }
    __syncthreads();
    // ---- all 4 code-groups in one pass: acc[4][8], xrow strip loaded once ----
    float acc[4][RPB];
#pragma unroll
    for (int g = 0; g < 4; ++g)
#pragma unroll
      for (int r = 0; r < RPB; ++r) acc[g][r] = 0.f;
    const float4* wrp0 = (const float4*)(w + (size_t)(0 * 256 + t) * DDIM);
    const float4* wrp1 = (const float4*)(w + (size_t)(1 * 256 + t) * DDIM);
    const float4* wrp2 = (const float4*)(w + (size_t)(2 * 256 + t) * DDIM);
    const float4* wrp3 = (const float4*)(w + (size_t)(3 * 256 + t) * DDIM);
    for (int d4 = 0; d4 < DDIM / 4; ++d4) {
      float4 xr4[RPB];
#pragma unroll
      for (int r = 0; r < RPB; ++r) xr4[r] = *(const float4*)&xrow[r][d4 * 4];  // b128, broadcast
      const float4 wv0 = wrp0[d4], wv1 = wrp1[d4], wv2 = wrp2[d4], wv3 = wrp3[d4];
#pragma unroll
      for (int e = 0; e < 4; ++e) {
        const float w0 = (e == 0) ? wv0.x : (e == 1) ? wv0.y : (e == 2) ? wv0.z : wv0.w;
        const float w1 = (e == 0) ? wv1.x : (e == 1) ? wv1.y : (e == 2) ? wv1.z : wv1.w;
        const float w2 = (e == 0) ? wv2.x : (e == 1) ? wv2.y : (e == 2) ? wv2.z : wv2.w;
        const float w3 = (e == 0) ? wv3.x : (e == 1) ? wv3.y : (e == 2) ? wv3.z : wv3.w;
#pragma unroll
        for (int r = 0; r < RPB; ++r) {
          const float xv = (e == 0) ? xr4[r].x : (e == 1) ? xr4[r].y : (e == 2) ? xr4[r].z : xr4[r].w;
          acc[0][r] = fmaf(xv, w0, acc[0][r]);
          acc[1][r] = fmaf(xv, w1, acc[1][r]);
          acc[2][r] = fmaf(xv, w2, acc[2][r]);
          acc[3][r] = fmaf(xv, w3, acc[3][r]);
        }
      }
    }
    float bD[RPB]; int bI[RPB];
#pragma unroll
    for (int r = 0; r < RPB; ++r) { bD[r] = 3.4e38f; bI[r] = 0x7fffffff; }
#pragma unroll
    for (int g = 0; g < 4; ++g) {
      const int c = g * 256 + t;
      const float swc = sw[c];
#pragma unroll
      for (int r = 0; r < RPB; ++r) {
        // dist = fl(fl(sx+sw) - 2*dot); g ascending => lowest code wins ties
        const float tt = sxsh[r] + swc;
        const float dist = tt - 2.0f * acc[g][r];
        if (dist < bD[r]) { bD[r] = dist; bI[r] = c; }
      }
    }
    // lexicographic (dist, idx) min: wave shuffle reduce, then 4-entry cross-wave merge.
#pragma unroll
    for (int off = 32; off > 0; off >>= 1) {
#pragma unroll
      for (int r = 0; r < RPB; ++r) {
        const float od = __shfl_down(bD[r], off);
        const int oi = __shfl_down(bI[r], off);
        if (od < bD[r] || (od == bD[r] && oi < bI[r])) { bD[r] = od; bI[r] = oi; }
      }
    }
    if (lane == 0) {
#pragma unroll
      for (int r = 0; r < RPB; ++r) { redD[r][wvid] = bD[r]; redI[r][wvid] = bI[r]; }
    }
    __syncthreads();
    if (t < nr) {
      float bb = redD[t][0]; int bix = redI[t][0];
#pragma unroll
      for (int k = 1; k < 4; ++k) {
        const float od = redD[t][k]; const int oi = redI[t][k];
        if (od < bb || (od == bb && oi < bix)) { bb = od; bix = oi; }
      }
      const int row = flagList[base + t];
      idxOut[row] = bix;
      idxOutF[row] = (float)bix;
    }
  }
}

// ====== gather + straight-through out + qloss partial + histogram (batched loads) ======
__global__ __launch_bounds__(256) void vq_quantize(const float* __restrict__ x,
                                                   const float* __restrict__ w,
                                                   const int* __restrict__ idxArr,
                                                   float* __restrict__ qout,
                                                   int* __restrict__ counts,
                                                   float* __restrict__ partialQ) {
  const int wave = threadIdx.x >> 6;
  const int lane = threadIdx.x & 63;
  const int base = blockIdx.x * 64 + wave * 16;
  float s = 0.f;
#pragma unroll
  for (int rg = 0; rg < 4; ++rg) {
    int idx4[4];
#pragma unroll
    for (int r = 0; r < 4; ++r) idx4[r] = idxArr[base + rg * 4 + r];
    float4 xv[4], qv[4];
#pragma unroll
    for (int r = 0; r < 4; ++r) {
      xv[r] = ((const float4*)(x + (size_t)(base + rg * 4 + r) * DDIM))[lane];
      qv[r] = ((const float4*)(w + (size_t)idx4[r] * DDIM))[lane];
    }
#pragma unroll
    for (int r = 0; r < 4; ++r) {
      const int row = base + rg * 4 + r;
      float dx = qv[r].x - xv[r].x, dy = qv[r].y - xv[r].y;
      float dz = qv[r].z - xv[r].z, dw = qv[r].w - xv[r].w;
      float4 o;
      o.x = xv[r].x + dx; o.y = xv[r].y + dy; o.z = xv[r].z + dz; o.w = xv[r].w + dw;
      ((float4*)(qout + (size_t)row * DDIM))[lane] = o;
      s += dx * dx + dy * dy + dz * dz + dw * dw;
      if (lane == 0) atomicAdd(&counts[idx4[r]], 1);
    }
  }
  double d = s;
  for (int off = 32; off > 0; off >>= 1) d += __shfl_down(d, off);
  __shared__ double red[4];
  if (lane == 0) red[wave] = d;
  __syncthreads();
  if (threadIdx.x == 0)
    partialQ[blockIdx.x] = (float)(red[0] + red[1] + red[2] + red[3]);
}

// ========== finalize ==========
__global__ __launch_bounds__(1024) void vq_final(const float* __restrict__ partialQ,
                                                 const float* __restrict__ partialP,
                                                 const int* __restrict__ counts,
                                                 float* __restrict__ out) {
  const int t = threadIdx.x;
  const int lane = t & 63, wave = t >> 6;
  double q = (double)partialQ[t];
  double p = (double)partialP[t];
  double u = (double)fabsf((float)counts[t] - 64.0f);
  for (int off = 32; off > 0; off >>= 1) {
    q += __shfl_down(q, off);
    p += __shfl_down(p, off);
    u += __shfl_down(u, off);
  }
  __shared__ double redQ[16], redP[16], redU[16];
  if (lane == 0) { redQ[wave] = q; redP[wave] = p; redU[wave] = u; }
  __syncthreads();
  if (t == 0) {
    double sq = 0, sp = 0, su = 0;
    for (int j = 0; j < 16; ++j) { sq += redQ[j]; sp += redP[j]; su += redU[j]; }
    float m = (float)(sq / 16777216.0);
    out[ND_TOT] = m + 0.25f * m;
    out[ND_TOT + 1] = (float)(su / 1024.0);
    out[ND_TOT + 2] = (float)(2.0 * sp / 523776.0);
  }
}

extern "C" void kernel_launch(void* const* d_in, const int* in_sizes, int n_in,
                              void* d_out, int out_size, void* d_ws, size_t ws_size,
                              hipStream_t stream) {
  const float* x = (const float*)d_in[0];
  const float* w = (const float*)d_in[1];
  float* out = (float*)d_out;

  char* ws = (char*)d_ws;
  int* wsIdx    = (int*)(ws + WS_IDX);
  int* counts   = (int*)(ws + WS_COUNTS);
  float* swv    = (float*)(ws + WS_SW);
  float* partQ  = (float*)(ws + WS_PARTQ);
  float* partP  = (float*)(ws + WS_PARTP);
  int* flagCnt  = (int*)(ws + WS_FLAGCNT);
  int* flagList = (int*)(ws + WS_FLAGLIST);
  unsigned short* whS = (unsigned short*)(ws + WS_WH);
  unsigned short* wlS = (unsigned short*)(ws + WS_WL);

  // bf16 splits of x live in the quantized-output region (overwritten by vq_quantize later)
  unsigned short* xhS = (unsigned short*)d_out;
  unsigned short* xlS = xhS + (size_t)ND_TOT;

  hipMemsetAsync(ws + WS_PARTP, 0, 4096, stream);  // compact accumulators

  vq_prep<<<4384, 256, 0, stream>>>(x, w, xhS, xlS, swv, whS, wlS, counts, flagCnt, partP);
  vq_argmin_mfma<<<NROWS / TRM, 256, 0, stream>>>(xhS, xlS, whS, wlS, swv,
                                                  wsIdx, out + ND_TOT + 3, flagCnt, flagList);
  vq_repair<<<1024, 256, 0, stream>>>(x, w, swv, flagCnt, flagList, wsIdx, out + ND_TOT + 3);
  vq_quantize<<<1024, 256, 0, stream>>>(x, w, wsIdx, out, counts, partQ);
  vq_final<<<1, 1024, 0, stream>>>(partQ, partP, counts, out);
}

// Round 20
// 227.119 us; speedup vs baseline: 1.1003x; 1.1003x over previous
//
#include <hip/hip_runtime.h>
#include <math.h>

#define NROWS 65536
#define KCODES 1024
#define DDIM 256
#define ND_TOT (NROWS * DDIM)

// ---------- ws layout (bytes) ----------
#define WS_IDX      0         // int idx[N]          256KB
#define WS_COUNTS   262144    // int counts[K]       4KB
#define WS_SW       266240    // float sw[K]         4KB
#define WS_PARTQ    532480    // float partQ[1024]   4KB
#define WS_PARTP    536576    // float partP[1024]   4KB
#define WS_FLAGCNT  540672    // int                 (256B slot)
#define WS_FLAGLIST 540928    // int flagList[N]     256KB
#define WS_WH       803072    // ushort wh[K*256]    512KB
#define WS_WL       1327360   // ushort wl[K*256]    512KB

typedef float f32x4 __attribute__((ext_vector_type(4)));
typedef short bf16x8 __attribute__((ext_vector_type(8)));

__device__ inline unsigned short f2bf(float f) {
  unsigned u = __float_as_uint(f);
  u += 0x7FFFu + ((u >> 16) & 1u);   // RNE to bf16
  return (unsigned short)(u >> 16);
}
__device__ inline float bf2f(unsigned short h) {
  return __uint_as_float(((unsigned)h) << 16);
}

__device__ inline void gload16(const void* g, void* l) {
  __builtin_amdgcn_global_load_lds((const __attribute__((address_space(1))) void*)g,
                                   (__attribute__((address_space(3))) void*)l, 16, 0, 0);
}

// ========== fused prep ==========
// blocks [0,2048):    x bf16-split, batched loads; block 0 zeroes counts+flagCnt+partialP
// blocks [2048,2304): w prep: coalesced split + exact numpy-pairwise sw (lane chains)
__global__ __launch_bounds__(256) void vq_prep(const float* __restrict__ x,
                                               const float* __restrict__ w,
                                               unsigned short* __restrict__ xh,
                                               unsigned short* __restrict__ xl,
                                               float* __restrict__ sw,
                                               unsigned short* __restrict__ wh,
                                               unsigned short* __restrict__ wl,
                                               int* __restrict__ counts,
                                               int* __restrict__ flagCnt,
                                               float* __restrict__ partialP) {
#pragma clang fp contract(off)
  const int b = blockIdx.x;
  const int t = threadIdx.x;
  if (b >= 2048) {
    const int lane = t & 63, wv = t >> 6;
    const int row = (b - 2048) * 4 + wv;           // 256 blocks x 4 rows = 1024
    const float* src = w + (size_t)row * DDIM;
    float4 v4 = *(const float4*)&src[lane * 4];    // full row per wave, coalesced
    float fv[4] = {v4.x, v4.y, v4.z, v4.w};
    union { unsigned short us[4]; uint2 v; } ph, pl;
#pragma unroll
    for (int e = 0; e < 4; ++e) {
      unsigned short h = f2bf(fv[e]);
      ph.us[e] = h;
      pl.us[e] = f2bf(fv[e] - bf2f(h));
    }
    *(uint2*)&wh[(size_t)row * DDIM + lane * 4] = ph.v;
    *(uint2*)&wl[(size_t)row * DDIM + lane * 4] = pl.v;
    // exact sw: numpy pairwise_sum(256) = two 128-halves x 8 accumulators.
    float acc = 0.f;
    if (lane < 16) {
      const float* p = src + ((lane >> 3) & 1) * 128 + (lane & 7);
      float v = p[0];
      acc = v * v;
      for (int k = 1; k < 16; ++k) { float vv = p[k * 8]; float e = vv * vv; acc = acc + e; }
    }
    // tree combine in reference association order ((a0+a1)+(a2+a3))+((a4+a5)+(a6+a7))
    acc = acc + __shfl_xor(acc, 1);
    acc = acc + __shfl_xor(acc, 2);
    acc = acc + __shfl_xor(acc, 4);
    const float hb = __shfl(acc, 8);               // half-1 total sits at lane 8
    if (lane == 0) sw[row] = acc + hb;
    return;
  }
  if (b == 0) {
#pragma unroll
    for (int j = 0; j < 4; ++j) { counts[j * 256 + t] = 0; partialP[j * 256 + t] = 0.f; }
    if (t == 0) flagCnt[0] = 0;
  }
  // ---- x split: batch all 8 loads before converting (4x outstanding loads/wave) ----
  const size_t tid = (size_t)b * 256 + t;
  float4 a[4], c[4];
#pragma unroll
  for (int g = 0; g < 4; ++g) {
    const size_t e = ((size_t)g * 524288 + tid) * 8;
    a[g] = *(const float4*)&x[e];
    c[g] = *(const float4*)&x[e + 4];
  }
#pragma unroll
  for (int g = 0; g < 4; ++g) {
    const size_t e = ((size_t)g * 524288 + tid) * 8;
    float fv[8] = {a[g].x, a[g].y, a[g].z, a[g].w, c[g].x, c[g].y, c[g].z, c[g].w};
    union { unsigned short us[8]; uint4 v; } ph, pl;
#pragma unroll
    for (int k = 0; k < 8; ++k) {
      unsigned short h = f2bf(fv[k]);
      ph.us[k] = h;
      pl.us[k] = f2bf(fv[k] - bf2f(h));   // exact in fp32
    }
    *(uint4*)&xh[e] = ph.v;
    *(uint4*)&xl[e] = pl.v;
  }
}

// ========== MFMA split-bf16 distance + top2 argmin (R14/R16 structure, proven 110us) ==========
// x-fragments in registers for full K; single-buffer w staging, 2 barriers/dt.
// NOTE (R17 lesson): double-buffered pipelining of this loop spills (WRITE_SIZE 90MB)
// and regresses to 152us — do not re-attempt at source level.
#define TRM 128
#define BKM 64
// Flag threshold: hard bound for a reference-order flip is
//   approx-e error (<=~6e-6) + reference rounding reorder width (~6.1e-5).
// Total ~7.3e-5; T=1.5e-4 keeps 2x margin.
#define REPAIR_T 1.5e-4f

__global__ __launch_bounds__(256, 2) void vq_argmin_mfma(
    const unsigned short* __restrict__ xh, const unsigned short* __restrict__ xl,
    const unsigned short* __restrict__ wh, const unsigned short* __restrict__ wl,
    const float* __restrict__ sw,
    int* __restrict__ idxOut, float* __restrict__ idxOutF,
    int* __restrict__ flagCnt, int* __restrict__ flagList) {
  __shared__ __align__(16) unsigned short lds_wh[TRM * BKM];  // 16KB each, XOR-swizzled
  __shared__ __align__(16) unsigned short lds_wl[TRM * BKM];
  __shared__ __align__(16) float sws[KCODES];
  __shared__ float mrgB1[TRM];
  __shared__ float mrgB2[TRM];
  __shared__ int   mrgI[TRM];

  const int t = threadIdx.x;
  const int lane = t & 63, wv = t >> 6;   // 4 waves; wave owns rows [wv*32, wv*32+32)
  const int row0 = blockIdx.x * TRM;

  { f32x4 v = ((const f32x4*)sw)[t]; ((f32x4*)sws)[t] = v; }  // 1024 floats

  const int laneRow = lane >> 3;                                  // 0..7
  const int srcswz = ((lane & 7) * 16) ^ ((laneRow & 7) << 4);    // pre-swizzled source chunk
  const char* whB = (const char*)wh;
  const char* wlB = (const char*)wl;

  // ---- one-time x fragment preload: register image == what the LDS path produced ----
  bf16x8 ah[2][8], al[2][8];
  {
    const int rbase = row0 + wv * 32 + (lane & 15);
    const int kof = ((lane >> 4) & 3) * 8;
#pragma unroll
    for (int i = 0; i < 2; ++i)
#pragma unroll
      for (int ks = 0; ks < 8; ++ks) {
        const size_t e = (size_t)(rbase + i * 16) * DDIM + (size_t)(ks * 32 + kof);
        ah[i][ks] = *(const bf16x8*)&xh[e];
        al[i][ks] = *(const bf16x8*)&xl[e];
      }
  }

  float b1[8], b2[8];
  int bi[8];
#pragma unroll
  for (int s = 0; s < 8; ++s) { b1[s] = 3.4e38f; b2[s] = 3.4e38f; bi[s] = 0; }

  for (int ct = 0; ct < KCODES / TRM; ++ct) {
    f32x4 acc[2][8];
#pragma unroll
    for (int i = 0; i < 2; ++i)
#pragma unroll
      for (int j = 0; j < 8; ++j) acc[i][j] = (f32x4){0.f, 0.f, 0.f, 0.f};

    for (int dt = 0; dt < 4; ++dt) {
      __syncthreads();   // previous tile fully consumed
#pragma unroll
      for (int i = 0; i < 4; ++i) {
        const int rb = wv * 32 + i * 8;
        const size_t gow = (size_t)(ct * 128 + rb + laneRow) * 512 + (size_t)(dt * 128 + srcswz);
        gload16(whB + gow, (char*)lds_wh + rb * 128);
        gload16(wlB + gow, (char*)lds_wl + rb * 128);
      }
      __syncthreads();   // drains vmcnt + barrier

#pragma unroll
      for (int kh = 0; kh < 2; ++kh) {
        const int kb = kh * 64 + ((lane >> 4) & 3) * 16;
        const int ks = dt * 2 + kh;
#pragma unroll
        for (int j = 0; j < 8; ++j) {
          const int c = j * 16 + (lane & 15);
          const int off = c * 128 + (kb ^ ((c & 7) << 4));
          bf16x8 bh = *(const bf16x8*)((const char*)lds_wh + off);
          bf16x8 bl = *(const bf16x8*)((const char*)lds_wl + off);
#pragma unroll
          for (int i = 0; i < 2; ++i) {
            acc[i][j] = __builtin_amdgcn_mfma_f32_16x16x32_bf16(ah[i][ks], bh, acc[i][j], 0, 0, 0);
            acc[i][j] = __builtin_amdgcn_mfma_f32_16x16x32_bf16(ah[i][ks], bl, acc[i][j], 0, 0, 0);
            acc[i][j] = __builtin_amdgcn_mfma_f32_16x16x32_bf16(al[i][ks], bh, acc[i][j], 0, 0, 0);
          }
        }
      }
    }

    // top-2 update in e-space: e = sw - 2*dot  (sx drops out of per-row argmin)
#pragma unroll
    for (int j = 0; j < 8; ++j) {
      const int colbase = ct * 128 + j * 16 + (lane & 15);
      const float swv = sws[colbase];
#pragma unroll
      for (int i = 0; i < 2; ++i)
#pragma unroll
        for (int q = 0; q < 4; ++q) {
          const int s = i * 4 + q;
          const float e = fmaf(-2.f, acc[i][j][q], swv);
          const bool c1 = e < b1[s];
          b2[s] = c1 ? b1[s] : fminf(b2[s], e);
          bi[s] = c1 ? colbase : bi[s];
          b1[s] = fminf(b1[s], e);
        }
    }
  }

  // merge across the 16 lanes sharing rows (lane&15 varies = different cols)
#pragma unroll
  for (int off = 1; off < 16; off <<= 1) {
#pragma unroll
    for (int s = 0; s < 8; ++s) {
      const float ob1 = __shfl_xor(b1[s], off);
      const float ob2 = __shfl_xor(b2[s], off);
      const int oi = __shfl_xor(bi[s], off);
      const float hi = fmaxf(b1[s], ob1);
      const bool take = ob1 < b1[s];
      b1[s] = fminf(b1[s], ob1);
      b2[s] = fminf(hi, fminf(b2[s], ob2));
      bi[s] = take ? oi : bi[s];
    }
  }
  if ((lane & 15) == 0) {
#pragma unroll
    for (int i = 0; i < 2; ++i)
#pragma unroll
      for (int q = 0; q < 4; ++q) {
        const int s = i * 4 + q;
        const int r = wv * 32 + i * 16 + ((lane >> 4) & 3) * 4 + q;
        mrgB1[r] = b1[s]; mrgB2[r] = b2[s]; mrgI[r] = bi[s];
      }
  }
  __syncthreads();
  if (t < TRM) {
    const float b1f = mrgB1[t];
    const float b2f = mrgB2[t];
    const int idxf = mrgI[t];
    const int grow = row0 + t;
    idxOut[grow] = idxf;
    idxOutF[grow] = (float)idxf;
    const bool flag = (b2f - b1f) < REPAIR_T;
    unsigned long long m = __ballot(flag);
    int base2 = 0;
    if ((t & 63) == 0) base2 = atomicAdd(flagCnt, __popcll(m));
    base2 = __shfl(base2, 0);
    if (flag) flagList[base2 + __popcll(m & ((1ull << (t & 63)) - 1ull))] = grow;
  }
}

// ========== fused: exact repair of flagged rows + tiled coalesced compactness ==========
// blocks [0,1024): repair (RPB=8); blocks [1024,1552): compact tile b-1024
#define RPB 8
#define CTI 32
#define CPAD 260
__global__ __launch_bounds__(256) void vq_repair_compact(
    const float* __restrict__ x, const float* __restrict__ w,
    const float* __restrict__ sw,
    const int* __restrict__ flagCnt, const int* __restrict__ flagList,
    int* __restrict__ idxOut, float* __restrict__ idxOutF,
    float* __restrict__ partialP) {
  const int t = threadIdx.x;
  const int lane = t & 63, wvid = t >> 6;
  if (blockIdx.x >= 1024) {
    // ---- compactness: 32x32-pair tile, both panels staged coalesced ----
    __shared__ __align__(16) float wI[CTI][CPAD];
    __shared__ __align__(16) float wJ[CTI][CPAD];
    int b = blockIdx.x - 1024, ti = 0;
    while (b >= 32 - ti) { b -= 32 - ti; ++ti; }
    const int tj = ti + b;
#pragma unroll
    for (int k = 0; k < 8; ++k) {
      const int q = k * 256 + t;
      const int r = q >> 6, c4 = q & 63;
      float4 vI = *(const float4*)&w[(size_t)(ti * CTI + r) * DDIM + c4 * 4];
      float4 vJ = *(const float4*)&w[(size_t)(tj * CTI + r) * DDIM + c4 * 4];
      *(float4*)&wI[r][c4 * 4] = vI;
      *(float4*)&wJ[r][c4 * 4] = vJ;
    }
    __syncthreads();
    const int ia = 2 * (t & 15);
    const int jc = 2 * (t >> 4);
    float a00 = 0.f, a01 = 0.f, a10 = 0.f, a11 = 0.f;
    for (int d4 = 0; d4 < DDIM / 4; ++d4) {
      const float4 A0 = *(const float4*)&wI[ia][d4 * 4];
      const float4 A1 = *(const float4*)&wI[ia + 1][d4 * 4];
      const float4 B0 = *(const float4*)&wJ[jc][d4 * 4];
      const float4 B1 = *(const float4*)&wJ[jc + 1][d4 * 4];
      a00 += A0.x * B0.x + A0.y * B0.y + A0.z * B0.z + A0.w * B0.w;
      a01 += A0.x * B1.x + A0.y * B1.y + A0.z * B1.z + A0.w * B1.w;
      a10 += A1.x * B0.x + A1.y * B0.y + A1.z * B0.z + A1.w * B0.w;
      a11 += A1.x * B1.x + A1.y * B1.y + A1.z * B1.z + A1.w * B1.w;
    }
    double s = 0.0;
    {
      const int i0 = ti * CTI + ia, j0 = tj * CTI + jc;
      const float acc2[2][2] = {{a00, a01}, {a10, a11}};
#pragma unroll
      for (int ii = 0; ii < 2; ++ii)
#pragma unroll
        for (int jj = 0; jj < 2; ++jj) {
          const int i = i0 + ii, j = j0 + jj;
          if (i < j) {
            const float pd2 = (sw[i] + sw[j]) - 2.0f * acc2[ii][jj];
            s += (double)sqrtf(fmaxf(pd2, 1e-12f));
          }
        }
    }
    for (int off = 32; off > 0; off >>= 1) s += __shfl_down(s, off);
    __shared__ double redc[4];
    if (lane == 0) redc[wvid] = s;
    __syncthreads();
    if (t == 0) partialP[blockIdx.x - 1024] = (float)(redc[0] + redc[1] + redc[2] + redc[3]);
    return;
  }
  // ---- repair ----
  __shared__ __align__(16) float xrow[RPB][DDIM];
  __shared__ float sxsh[RPB];
  __shared__ float redD[RPB][4];
  __shared__ int   redI[RPB][4];
  const int cnt = flagCnt[0];
  for (int base = blockIdx.x * RPB; base < cnt; base += 1024 * RPB) {
    const int nr = min(RPB, cnt - base);
    __syncthreads();   // protect xrow/redD from previous pass readers
    for (int r = 0; r < nr; ++r)
      xrow[r][t] = x[(size_t)flagList[base + r] * DDIM + t];
    __syncthreads();
    // exact sx for this row: numpy pairwise order, no FMA
    if (t < nr) {
#pragma clang fp contract(off)
      float halves[2];
#pragma unroll
      for (int h = 0; h < 2; ++h) {
        const float* p = &xrow[t][h * 128];
        float acc[8];
#pragma unroll
        for (int j = 0; j < 8; ++j) { float v = p[j]; acc[j] = v * v; }
        for (int i = 8; i < 128; i += 8) {
#pragma unroll
          for (int j = 0; j < 8; ++j) { float v = p[i + j]; float e = v * v; acc[j] = acc[j] + e; }
        }
        halves[h] = ((acc[0] + acc[1]) + (acc[2] + acc[3])) + ((acc[4] + acc[5]) + (acc[6] + acc[7]));
      }
      sxsh[t] = halves[0] + halves[1];
    }
    __syncthreads();
    // ---- all 4 code-groups in one pass: acc[4][8], xrow strip loaded once ----
    float acc[4][RPB];
#pragma unroll
    for (int g = 0; g < 4; ++g)
#pragma unroll
      for (int r = 0; r < RPB; ++r) acc[g][r] = 0.f;
    const float4* wrp0 = (const float4*)(w + (size_t)(0 * 256 + t) * DDIM);
    const float4* wrp1 = (const float4*)(w + (size_t)(1 * 256 + t) * DDIM);
    const float4* wrp2 = (const float4*)(w + (size_t)(2 * 256 + t) * DDIM);
    const float4* wrp3 = (const float4*)(w + (size_t)(3 * 256 + t) * DDIM);
    for (int d4 = 0; d4 < DDIM / 4; ++d4) {
      float4 xr4[RPB];
#pragma unroll
      for (int r = 0; r < RPB; ++r) xr4[r] = *(const float4*)&xrow[r][d4 * 4];  // b128, broadcast
      const float4 wv0 = wrp0[d4], wv1 = wrp1[d4], wv2 = wrp2[d4], wv3 = wrp3[d4];
#pragma unroll
      for (int e = 0; e < 4; ++e) {
        const float w0 = (e == 0) ? wv0.x : (e == 1) ? wv0.y : (e == 2) ? wv0.z : wv0.w;
        const float w1 = (e == 0) ? wv1.x : (e == 1) ? wv1.y : (e == 2) ? wv1.z : wv1.w;
        const float w2 = (e == 0) ? wv2.x : (e == 1) ? wv2.y : (e == 2) ? wv2.z : wv2.w;
        const float w3 = (e == 0) ? wv3.x : (e == 1) ? wv3.y : (e == 2) ? wv3.z : wv3.w;
#pragma unroll
        for (int r = 0; r < RPB; ++r) {
          const float xv = (e == 0) ? xr4[r].x : (e == 1) ? xr4[r].y : (e == 2) ? xr4[r].z : xr4[r].w;
          acc[0][r] = fmaf(xv, w0, acc[0][r]);
          acc[1][r] = fmaf(xv, w1, acc[1][r]);
          acc[2][r] = fmaf(xv, w2, acc[2][r]);
          acc[3][r] = fmaf(xv, w3, acc[3][r]);
        }
      }
    }
    float bD[RPB]; int bI[RPB];
#pragma unroll
    for (int r = 0; r < RPB; ++r) { bD[r] = 3.4e38f; bI[r] = 0x7fffffff; }
#pragma unroll
    for (int g = 0; g < 4; ++g) {
      const int c = g * 256 + t;
      const float swc = sw[c];
#pragma unroll
      for (int r = 0; r < RPB; ++r) {
        // dist = fl(fl(sx+sw) - 2*dot); g ascending => lowest code wins ties
        const float tt = sxsh[r] + swc;
        const float dist = tt - 2.0f * acc[g][r];
        if (dist < bD[r]) { bD[r] = dist; bI[r] = c; }
      }
    }
    // lexicographic (dist, idx) min: wave shuffle reduce, then 4-entry cross-wave merge.
#pragma unroll
    for (int off = 32; off > 0; off >>= 1) {
#pragma unroll
      for (int r = 0; r < RPB; ++r) {
        const float od = __shfl_down(bD[r], off);
        const int oi = __shfl_down(bI[r], off);
        if (od < bD[r] || (od == bD[r] && oi < bI[r])) { bD[r] = od; bI[r] = oi; }
      }
    }
    if (lane == 0) {
#pragma unroll
      for (int r = 0; r < RPB; ++r) { redD[r][wvid] = bD[r]; redI[r][wvid] = bI[r]; }
    }
    __syncthreads();
    if (t < nr) {
      float bb = redD[t][0]; int bix = redI[t][0];
#pragma unroll
      for (int k = 1; k < 4; ++k) {
        const float od = redD[t][k]; const int oi = redI[t][k];
        if (od < bb || (od == bb && oi < bix)) { bb = od; bix = oi; }
      }
      const int row = flagList[base + t];
      idxOut[row] = bix;
      idxOutF[row] = (float)bix;
    }
  }
}

// ====== gather + straight-through out + qloss partial + histogram (batched loads) ======
__global__ __launch_bounds__(256) void vq_quantize(const float* __restrict__ x,
                                                   const float* __restrict__ w,
                                                   const int* __restrict__ idxArr,
                                                   float* __restrict__ qout,
                                                   int* __restrict__ counts,
                                                   float* __restrict__ partialQ) {
  const int wave = threadIdx.x >> 6;
  const int lane = threadIdx.x & 63;
  const int base = blockIdx.x * 64 + wave * 16;
  float s = 0.f;
#pragma unroll
  for (int rg = 0; rg < 4; ++rg) {
    int idx4[4];
#pragma unroll
    for (int r = 0; r < 4; ++r) idx4[r] = idxArr[base + rg * 4 + r];
    float4 xv[4], qv[4];
#pragma unroll
    for (int r = 0; r < 4; ++r) {
      xv[r] = ((const float4*)(x + (size_t)(base + rg * 4 + r) * DDIM))[lane];
      qv[r] = ((const float4*)(w + (size_t)idx4[r] * DDIM))[lane];
    }
#pragma unroll
    for (int r = 0; r < 4; ++r) {
      const int row = base + rg * 4 + r;
      float dx = qv[r].x - xv[r].x, dy = qv[r].y - xv[r].y;
      float dz = qv[r].z - xv[r].z, dw = qv[r].w - xv[r].w;
      float4 o;
      o.x = xv[r].x + dx; o.y = xv[r].y + dy; o.z = xv[r].z + dz; o.w = xv[r].w + dw;
      ((float4*)(qout + (size_t)row * DDIM))[lane] = o;
      s += dx * dx + dy * dy + dz * dz + dw * dw;
      if (lane == 0) atomicAdd(&counts[idx4[r]], 1);
    }
  }
  double d = s;
  for (int off = 32; off > 0; off >>= 1) d += __shfl_down(d, off);
  __shared__ double red[4];
  if (lane == 0) red[wave] = d;
  __syncthreads();
  if (threadIdx.x == 0)
    partialQ[blockIdx.x] = (float)(red[0] + red[1] + red[2] + red[3]);
}

// ========== finalize ==========
__global__ __launch_bounds__(1024) void vq_final(const float* __restrict__ partialQ,
                                                 const float* __restrict__ partialP,
                                                 const int* __restrict__ counts,
                                                 float* __restrict__ out) {
  const int t = threadIdx.x;
  const int lane = t & 63, wave = t >> 6;
  double q = (double)partialQ[t];
  double p = (double)partialP[t];
  double u = (double)fabsf((float)counts[t] - 64.0f);
  for (int off = 32; off > 0; off >>= 1) {
    q += __shfl_down(q, off);
    p += __shfl_down(p, off);
    u += __shfl_down(u, off);
  }
  __shared__ double redQ[16], redP[16], redU[16];
  if (lane == 0) { redQ[wave] = q; redP[wave] = p; redU[wave] = u; }
  __syncthreads();
  if (t == 0) {
    double sq = 0, sp = 0, su = 0;
    for (int j = 0; j < 16; ++j) { sq += redQ[j]; sp += redP[j]; su += redU[j]; }
    float m = (float)(sq / 16777216.0);
    out[ND_TOT] = m + 0.25f * m;
    out[ND_TOT + 1] = (float)(su / 1024.0);
    out[ND_TOT + 2] = (float)(2.0 * sp / 523776.0);
  }
}

extern "C" void kernel_launch(void* const* d_in, const int* in_sizes, int n_in,
                              void* d_out, int out_size, void* d_ws, size_t ws_size,
                              hipStream_t stream) {
  const float* x = (const float*)d_in[0];
  const float* w = (const float*)d_in[1];
  float* out = (float*)d_out;

  char* ws = (char*)d_ws;
  int* wsIdx    = (int*)(ws + WS_IDX);
  int* counts   = (int*)(ws + WS_COUNTS);
  float* swv    = (float*)(ws + WS_SW);
  float* partQ  = (float*)(ws + WS_PARTQ);
  float* partP  = (float*)(ws + WS_PARTP);
  int* flagCnt  = (int*)(ws + WS_FLAGCNT);
  int* flagList = (int*)(ws + WS_FLAGLIST);
  unsigned short* whS = (unsigned short*)(ws + WS_WH);
  unsigned short* wlS = (unsigned short*)(ws + WS_WL);

  // bf16 splits of x live in the quantized-output region (overwritten by vq_quantize later)
  unsigned short* xhS = (unsigned short*)d_out;
  unsigned short* xlS = xhS + (size_t)ND_TOT;

  vq_prep<<<2304, 256, 0, stream>>>(x, w, xhS, xlS, swv, whS, wlS, counts, flagCnt, partP);
  vq_argmin_mfma<<<NROWS / TRM, 256, 0, stream>>>(xhS, xlS, whS, wlS, swv,
                                                  wsIdx, out + ND_TOT + 3, flagCnt, flagList);
  vq_repair_compact<<<1552, 256, 0, stream>>>(x, w, swv, flagCnt, flagList,
                                              wsIdx, out + ND_TOT + 3, partP);
  vq_quantize<<<1024, 256, 0, stream>>>(x, w, wsIdx, out, counts, partQ);
  vq_final<<<1, 1024, 0, stream>>>(partQ, partP, counts, out);
}